// Round 5
// baseline (245.828 us; speedup 1.0000x reference)
//
#include <hip/hip_runtime.h>

// ---------------------------------------------------------------------------
// sLSTM cell, B=8192, D=1024, H=1024.
//   pre[B,4H] = [x,h_prev] @ [Wg|Rg]^T  (K = D+H = 2048)
//   i=exp(pi+bi), f=sig(pf+bf), o=sig(po+bo), z=tanh(pz+bz)
//   c=f*c_prev+i*z ; n=f*n_prev+i ; m=max(log f + m_prev, pi) ; h=o*c/n
//   outputs (flat): h, c, C_prev(copy), n, m  -- each B*H f32
//
// Round 5: 256x256 8-phase deep-pipelined GEMM (m201-class template) with
// fused lane-local epilogue. 8 waves (2M x 4N), per-wave 128x64, BK=64,
// LDS = 2 dbuf x [256][64] x {A,B} = 128KB. Per K-tile 4 phases:
//   {ds_read subtile || stage 1 half-tile} -> barrier -> setprio+16 MFMA
//   -> barrier.  Staging ledger (per tile t, dbuf d=t&1):
//   p0: stage A-h0(t+1)->d^1   (A-h0(d^1) last read tile t-1, ended)
//   p1: stage A-h1(t+1)->d^1
//   p2: stage B-h0(t+2)->d     (B halves read ONLY in p0 -> free)
//   p3: stage B-h1(t+2)->d ; vmcnt(4) ; barrier
//   vmcnt(4) retires tile t+1's 8 loads, leaves t+2's B (4) in flight --
//   never drains to 0 until the tail. Per-lane issue count uniform (2/phase).
// Gate-interleaved W packing -> epilogue fully lane-local.
// ---------------------------------------------------------------------------

#define B_SZ 8192
#define D_SZ 1024
#define H_SZ 1024
#define K_SZ 2048   // D + H
#define N4H  4096   // 4*H

typedef __attribute__((ext_vector_type(4))) float f32x4;
typedef _Float16 f16;
typedef __attribute__((ext_vector_type(8))) f16 f16x8;
typedef unsigned short u16;
typedef __attribute__((ext_vector_type(4))) unsigned short u16x4;

static __device__ __forceinline__ u16 f2h(float f) {
    f16 h = (f16)f;
    return __builtin_bit_cast(unsigned short, h);
}

static __device__ __forceinline__ void load_lds16(const void* g, void* l) {
    __builtin_amdgcn_global_load_lds(
        (const __attribute__((address_space(1))) void*)g,
        (__attribute__((address_space(3))) void*)l, 16, 0, 0);
}

// ---------------------------------------------------------------------------
__global__ void convert_A(const float* __restrict__ x, const float* __restrict__ h,
                          u16* __restrict__ A) {
    const size_t nvec = (size_t)B_SZ * K_SZ / 4;
    const size_t stride = (size_t)gridDim.x * blockDim.x;
    for (size_t v = (size_t)blockIdx.x * blockDim.x + threadIdx.x; v < nvec; v += stride) {
        size_t e = v * 4;
        size_t row = e >> 11;
        int col = (int)(e & 2047);
        const float* src = (col < D_SZ) ? (x + row * D_SZ + col)
                                        : (h + row * H_SZ + (col - D_SZ));
        f32x4 val = *(const f32x4*)src;
        u16x4 o;
        o[0] = f2h(val[0]); o[1] = f2h(val[1]); o[2] = f2h(val[2]); o[3] = f2h(val[3]);
        *(u16x4*)(A + e) = o;
    }
}

// Pack W gate-interleaved: packed row r -> gate (r>>4)&3, j=(r>>6)*16+(r&15).
__global__ void convert_W(const float* __restrict__ Wi, const float* __restrict__ Wf,
                          const float* __restrict__ Wo, const float* __restrict__ Wz,
                          const float* __restrict__ Ri, const float* __restrict__ Rf,
                          const float* __restrict__ Ro, const float* __restrict__ Rz,
                          u16* __restrict__ Wb) {
    const size_t nvec = (size_t)N4H * K_SZ / 4;
    const size_t stride = (size_t)gridDim.x * blockDim.x;
    for (size_t v = (size_t)blockIdx.x * blockDim.x + threadIdx.x; v < nvec; v += stride) {
        size_t e = v * 4;
        size_t r = e >> 11;
        int col = (int)(e & 2047);
        int g = (int)(r >> 4) & 3;
        int j = (int)((r >> 6) << 4) | (int)(r & 15);
        const float* Wg = (g == 0) ? Wi : (g == 1) ? Wf : (g == 2) ? Wo : Wz;
        const float* Rg = (g == 0) ? Ri : (g == 1) ? Rf : (g == 2) ? Ro : Rz;
        const float* src = (col < D_SZ) ? (Wg + (size_t)j * D_SZ + col)
                                        : (Rg + (size_t)j * H_SZ + (col - D_SZ));
        f32x4 val = *(const f32x4*)src;
        u16x4 o;
        o[0] = f2h(val[0]); o[1] = f2h(val[1]); o[2] = f2h(val[2]); o[3] = f2h(val[3]);
        *(u16x4*)(Wb + e) = o;
    }
}

// ---------------------------------------------------------------------------
// 8-phase fused GEMM. 512 threads, 8 waves (wm = w>>2 in {0,1}, wn = w&3).
// ---------------------------------------------------------------------------
__global__ __launch_bounds__(512, 2)
void gemm_fused(const u16* __restrict__ A, const u16* __restrict__ W,
                const float* __restrict__ c_prev, const float* __restrict__ n_prev,
                const float* __restrict__ m_prev,
                const float* __restrict__ bi, const float* __restrict__ bfv,
                const float* __restrict__ bo, const float* __restrict__ bz,
                float* __restrict__ out) {
    __shared__ u16 lA[2][256 * 64];   // 64KB
    __shared__ u16 lB[2][256 * 64];   // 64KB

    const int tid = threadIdx.x;
    const int w   = tid >> 6;
    const int l   = tid & 63;
    const int wm  = w >> 2;            // 0..1 (128 M-rows each)
    const int wn  = w & 3;             // 0..3 (64 packed-cols each)
    const int m0  = blockIdx.x * 256;
    const int n0r = blockIdx.y * 256;

    const int lrow8 = l >> 3;                     // 0..7
    const int lseg  = (l & 7) ^ lrow8;            // pre-swizzled src segment
    const int laneOff = lrow8 * K_SZ + lseg * 8;  // per-lane global offset (u16)

    const int fr = l & 15;
    const int kq = l >> 4;

    const u16* Abase = A + (size_t)m0 * K_SZ + laneOff;
    const u16* Bbase = W + (size_t)n0r * K_SZ + laneOff;

    // stage one half-tile (128 rows x 64 K): 2 issues/thread, LDS linear.
    auto stA = [&](int h, int kt, int d) {
#pragma unroll
        for (int r = 0; r < 2; ++r)
            load_lds16(Abase + (size_t)(h * 128 + r * 64 + w * 8) * K_SZ + kt * 64,
                       (char*)&lA[d][0] + (h * 128 + r * 64 + w * 8) * 128);
    };
    auto stB = [&](int h, int kt, int d) {
#pragma unroll
        for (int r = 0; r < 2; ++r)
            load_lds16(Bbase + (size_t)(h * 128 + r * 64 + w * 8) * K_SZ + kt * 64,
                       (char*)&lB[d][0] + (h * 128 + r * 64 + w * 8) * 128);
    };

    f32x4 acc[8][4] = {};
    f16x8 bf[4][2];                    // wave's B-half frags, live whole tile

    auto rdB = [&](int d) {
#pragma unroll
        for (int ni = 0; ni < 4; ++ni)
#pragma unroll
            for (int ks = 0; ks < 2; ++ks) {
                int row = wn * 64 + ni * 16 + fr;
                int seg = (ks * 4 + kq) ^ (fr & 7);
                bf[ni][ks] = *(const f16x8*)&lB[d][row * 64 + seg * 8];
            }
    };

// One phase: ds_read A subtile (mi = 2p,2p+1) [+ all B at p0], stage, barrier,
// 16 MFMA (prio 1), tail-wait, barrier.  p/d are literals -> static indexing.
#define PHASE(d, p, STAGE, TAILWAIT)                                          \
    do {                                                                      \
        f16x8 af[2][2];                                                       \
        _Pragma("unroll")                                                     \
        for (int mi2 = 0; mi2 < 2; ++mi2)                                     \
            _Pragma("unroll")                                                 \
            for (int ks = 0; ks < 2; ++ks) {                                  \
                int row = wm * 128 + ((p) * 2 + mi2) * 16 + fr;               \
                int seg = (ks * 4 + kq) ^ (fr & 7);                           \
                af[mi2][ks] = *(const f16x8*)&lA[d][row * 64 + seg * 8];      \
            }                                                                 \
        if ((p) == 0) rdB(d);                                                 \
        STAGE;                                                                \
        __builtin_amdgcn_s_barrier();                                         \
        __builtin_amdgcn_s_setprio(1);                                        \
        _Pragma("unroll")                                                     \
        for (int mi2 = 0; mi2 < 2; ++mi2)                                     \
            _Pragma("unroll")                                                 \
            for (int ni = 0; ni < 4; ++ni)                                    \
                _Pragma("unroll")                                             \
                for (int ks = 0; ks < 2; ++ks)                                \
                    acc[(p) * 2 + mi2][ni] =                                  \
                        __builtin_amdgcn_mfma_f32_16x16x32_f16(               \
                            af[mi2][ks], bf[ni][ks], acc[(p) * 2 + mi2][ni],  \
                            0, 0, 0);                                         \
        __builtin_amdgcn_s_setprio(0);                                        \
        TAILWAIT;                                                             \
        __builtin_amdgcn_s_barrier();                                         \
    } while (0)

#define TILE_STEADY(t, d)                                                     \
    do {                                                                      \
        PHASE(d, 0, stA(0, (t) + 1, (d) ^ 1), (void)0);                       \
        PHASE(d, 1, stA(1, (t) + 1, (d) ^ 1), (void)0);                       \
        PHASE(d, 2, stB(0, (t) + 2, (d)), (void)0);                           \
        PHASE(d, 3, stB(1, (t) + 2, (d)),                                     \
              asm volatile("s_waitcnt vmcnt(4)" ::: "memory"));               \
    } while (0)

    // prologue: tile0 {A0,A1,B0,B1} + tile1 {B0,B1}; wait tile0 landed.
    stA(0, 0, 0); stA(1, 0, 0); stB(0, 0, 0); stB(1, 0, 0);
    stB(0, 1, 1); stB(1, 1, 1);
    asm volatile("s_waitcnt vmcnt(4)" ::: "memory");
    __builtin_amdgcn_s_barrier();

#pragma unroll 1
    for (int i = 0; i < 15; ++i) {
        int t = 2 * i;
        TILE_STEADY(t, 0);
        TILE_STEADY(t + 1, 1);
    }
    // tile 30 (d=0): stage tile31's A halves; drain at end.
    PHASE(0, 0, stA(0, 31, 1), (void)0);
    PHASE(0, 1, stA(1, 31, 1), (void)0);
    PHASE(0, 2, (void)0, (void)0);
    PHASE(0, 3, (void)0, asm volatile("s_waitcnt vmcnt(0)" ::: "memory"));
    // tile 31 (d=1): pure compute.
    PHASE(1, 0, (void)0, (void)0);
    PHASE(1, 1, (void)0, (void)0);
    PHASE(1, 2, (void)0, (void)0);
    PHASE(1, 3, (void)0, (void)0);
#undef TILE_STEADY
#undef PHASE

    // ---- fused sLSTM epilogue (fully lane-local) -------------------------
    const size_t BH = (size_t)B_SZ * H_SZ;
    const int j = ((n0r + wn * 64) >> 6) * 16 + fr;    // 0..1023
    const float bvi = bi[j], bvf = bfv[j], bvo = bo[j], bvz = bz[j];

#pragma unroll
    for (int mi = 0; mi < 8; ++mi) {
        const int rbase = m0 + wm * 128 + mi * 16 + kq * 4;
#pragma unroll
        for (int r2 = 0; r2 < 4; ++r2) {
            const size_t idx = (size_t)(rbase + r2) * H_SZ + j;
            float pi = acc[mi][0][r2] + bvi;
            float pf = acc[mi][1][r2] + bvf;
            float po = acc[mi][2][r2] + bvo;
            float pz = acc[mi][3][r2] + bvz;
            float iv = __expf(pi);
            float fv = 1.0f / (1.0f + __expf(-pf));
            float ov = 1.0f / (1.0f + __expf(-po));
            float e2 = __expf(2.0f * pz);
            float zv = 1.0f - 2.0f / (e2 + 1.0f);     // tanh(pz)
            float cv = fv * c_prev[idx] + iv * zv;
            float nv = fv * n_prev[idx] + iv;
            float mv = fmaxf(__logf(fv) + m_prev[idx], pi);
            out[idx]          = ov * (cv / nv);       // h
            out[BH + idx]     = cv;                   // c
            out[3 * BH + idx] = nv;                   // n
            out[4 * BH + idx] = mv;                   // m
        }
    }
}

// ---------------------------------------------------------------------------
extern "C" void kernel_launch(void* const* d_in, const int* in_sizes, int n_in,
                              void* d_out, int out_size, void* d_ws, size_t ws_size,
                              hipStream_t stream) {
    const float* x      = (const float*)d_in[0];
    const float* h_prev = (const float*)d_in[1];
    const float* c_prev = (const float*)d_in[2];
    const float* C_prev = (const float*)d_in[3];
    const float* n_prev = (const float*)d_in[4];
    const float* m_prev = (const float*)d_in[5];
    const float* Wz = (const float*)d_in[6];
    const float* bz = (const float*)d_in[7];
    const float* Rz = (const float*)d_in[8];
    const float* Wi = (const float*)d_in[9];
    const float* bi = (const float*)d_in[10];
    const float* Ri = (const float*)d_in[11];
    const float* Wf = (const float*)d_in[12];
    const float* bf = (const float*)d_in[13];
    const float* Rf = (const float*)d_in[14];
    const float* Wo = (const float*)d_in[15];
    const float* bo = (const float*)d_in[16];
    const float* Ro = (const float*)d_in[17];
    float* out = (float*)d_out;

    const size_t BH = (size_t)B_SZ * H_SZ;

    u16* Abuf = (u16*)d_ws;
    u16* Wbuf = (u16*)((char*)d_ws + (size_t)32 * 1024 * 1024);

    convert_A<<<2048, 256, 0, stream>>>(x, h_prev, Abuf);
    convert_W<<<2048, 256, 0, stream>>>(Wi, Wf, Wo, Wz, Ri, Rf, Ro, Rz, Wbuf);

    hipMemcpyAsync(out + 2 * BH, C_prev, BH * sizeof(float),
                   hipMemcpyDeviceToDevice, stream);

    gemm_fused<<<dim3(B_SZ / 256, N4H / 256), 512, 0, stream>>>(
        Abuf, Wbuf, c_prev, n_prev, m_prev, bi, bf, bo, bz, out);
}

// Round 6
// 218.709 us; speedup vs baseline: 1.1240x; 1.1240x over previous
//
#include <hip/hip_runtime.h>

// ---------------------------------------------------------------------------
// sLSTM cell, B=8192, D=1024, H=1024.
//   pre[B,4H] = [x,h_prev] @ [Wg|Rg]^T  (K = D+H = 2048)
//   i=exp(pi+bi), f=sig(pf+bf), o=sig(po+bo), z=tanh(pz+bz)
//   c=f*c_prev+i*z ; n=f*n_prev+i ; m=max(log f + m_prev, pi) ; h=o*c/n
//   outputs (flat): h, c, C_prev(copy), n, m  -- each B*H f32
//
// Round 6: consolidation on the round-2 structure (best measured fused GEMM).
//   - K-loop identical to round 2: 128x128 tile, BK=64, 4 waves, 32KB LDS,
//     2 syncthreads/tile, 3-4 blocks/CU (cross-block overlap hides staging).
//   - C_prev passthrough folded into the fused epilogue (kills the ~10us
//     serial hipMemcpyAsync in-stream).
//   - convert_A + convert_W merged into one grid-stride kernel (one launch).
//   - Epilogue loads batched per mi-block (16 parallel loads, then compute).
// Gate-interleaved W packing: packed row r -> gate (r>>4)&3,
// j=(r>>6)*16+(r&15) => a wave's 4 N-frags are {pi,pf,po,pz} of the same j.
// ---------------------------------------------------------------------------

#define B_SZ 8192
#define D_SZ 1024
#define H_SZ 1024
#define K_SZ 2048   // D + H
#define N4H  4096   // 4*H

typedef __attribute__((ext_vector_type(4))) float f32x4;
typedef _Float16 f16;
typedef __attribute__((ext_vector_type(8))) f16 f16x8;
typedef unsigned short u16;
typedef __attribute__((ext_vector_type(4))) unsigned short u16x4;

static __device__ __forceinline__ u16 f2h(float f) {
    f16 h = (f16)f;
    return __builtin_bit_cast(unsigned short, h);
}

static __device__ __forceinline__ void load_lds16(const void* g, void* l) {
    __builtin_amdgcn_global_load_lds(
        (const __attribute__((address_space(1))) void*)g,
        (__attribute__((address_space(3))) void*)l, 16, 0, 0);
}

// ---------------------------------------------------------------------------
// Merged pack kernel.
//   Part 1: A[B][K] = [x | h_prev] as fp16.
//   Part 2: W[4H][K] gate-interleaved fp16: packed row r -> gate g=(r>>4)&3,
//           j=(r>>6)*16+(r&15); content = [Wg[j,:] | Rg[j,:]].
// ---------------------------------------------------------------------------
__global__ void convert_AW(const float* __restrict__ x, const float* __restrict__ h,
                           const float* __restrict__ Wi, const float* __restrict__ Wf,
                           const float* __restrict__ Wo, const float* __restrict__ Wz,
                           const float* __restrict__ Ri, const float* __restrict__ Rf,
                           const float* __restrict__ Ro, const float* __restrict__ Rz,
                           u16* __restrict__ A, u16* __restrict__ Wb) {
    const size_t nvecA = (size_t)B_SZ * K_SZ / 4;
    const size_t nvecW = (size_t)N4H * K_SZ / 4;
    const size_t nvec  = nvecA + nvecW;
    const size_t stride = (size_t)gridDim.x * blockDim.x;
    for (size_t v = (size_t)blockIdx.x * blockDim.x + threadIdx.x; v < nvec; v += stride) {
        const float* src;
        u16* dst;
        if (v < nvecA) {
            size_t e = v * 4;
            size_t row = e >> 11;
            int col = (int)(e & 2047);
            src = (col < D_SZ) ? (x + row * D_SZ + col)
                               : (h + row * H_SZ + (col - D_SZ));
            dst = A + e;
        } else {
            size_t e = (v - nvecA) * 4;
            size_t r = e >> 11;                 // packed row 0..4095
            int col = (int)(e & 2047);
            int g = (int)(r >> 4) & 3;          // gate
            int j = (int)((r >> 6) << 4) | (int)(r & 15);
            const float* Wg = (g == 0) ? Wi : (g == 1) ? Wf : (g == 2) ? Wo : Wz;
            const float* Rg = (g == 0) ? Ri : (g == 1) ? Rf : (g == 2) ? Ro : Rz;
            src = (col < D_SZ) ? (Wg + (size_t)j * D_SZ + col)
                               : (Rg + (size_t)j * H_SZ + (col - D_SZ));
            dst = Wb + e;
        }
        f32x4 val = *(const f32x4*)src;
        u16x4 o;
        o[0] = f2h(val[0]); o[1] = f2h(val[1]); o[2] = f2h(val[2]); o[3] = f2h(val[3]);
        *(u16x4*)dst = o;
    }
}

// ---------------------------------------------------------------------------
// Fused GEMM + sLSTM epilogue (round-2 structure). 256 threads, 4 waves.
// ---------------------------------------------------------------------------
__global__ __launch_bounds__(256, 2)
void gemm_fused(const u16* __restrict__ A, const u16* __restrict__ W,
                const float* __restrict__ c_prev, const float* __restrict__ C_prev,
                const float* __restrict__ n_prev, const float* __restrict__ m_prev,
                const float* __restrict__ bi, const float* __restrict__ bfv,
                const float* __restrict__ bo, const float* __restrict__ bz,
                float* __restrict__ out) {
    __shared__ u16 lA[128 * 64];   // 16 KB
    __shared__ u16 lB[128 * 64];   // 16 KB

    const int tid = threadIdx.x;
    const int w  = tid >> 6;       // wave 0..3
    const int l  = tid & 63;       // lane
    const int wm = w >> 1;         // wave row (2)
    const int wn = w & 1;          // wave col (2)
    const int m0 = blockIdx.x * 128;
    const int n0 = blockIdx.y * 128;

    const int lrow8 = l >> 3;            // row within the wave's 8-row stripe
    const int lseg  = (l & 7) ^ lrow8;   // pre-swizzled global 16B-segment index

    const int fr = l & 15;   // fragment row (M for A, N for B), also C col
    const int kq = l >> 4;   // k-quad 0..3

    f32x4 acc[4][4] = {};

    for (int kt = 0; kt < K_SZ; kt += 64) {
        // ---- stage: 4 rounds x (A,B); each wave moves 1KB per call -------
#pragma unroll
        for (int r = 0; r < 4; ++r) {
            int rowA = r * 32 + w * 8 + lrow8;               // 0..127
            const u16* gA = A + (size_t)(m0 + rowA) * K_SZ + kt + lseg * 8;
            load_lds16(gA, (char*)lA + (r * 32 + w * 8) * 128);
            const u16* gB = W + (size_t)(n0 + rowA) * K_SZ + kt + lseg * 8;
            load_lds16(gB, (char*)lB + (r * 32 + w * 8) * 128);
        }
        __syncthreads();

        // ---- compute: 2 k-slices of 32, 4x4 frags ------------------------
#pragma unroll
        for (int ks = 0; ks < 2; ++ks) {
            f16x8 af[4], bfr[4];
#pragma unroll
            for (int mi = 0; mi < 4; ++mi) {
                int row = wm * 64 + mi * 16 + fr;
                int seg = (ks * 4 + kq) ^ (row & 7);
                af[mi] = *(const f16x8*)&lA[row * 64 + seg * 8];
            }
#pragma unroll
            for (int ni = 0; ni < 4; ++ni) {
                int row = wn * 64 + ni * 16 + fr;
                int seg = (ks * 4 + kq) ^ (row & 7);
                bfr[ni] = *(const f16x8*)&lB[row * 64 + seg * 8];
            }
            __builtin_amdgcn_s_setprio(1);
#pragma unroll
            for (int mi = 0; mi < 4; ++mi)
#pragma unroll
                for (int ni = 0; ni < 4; ++ni)
                    acc[mi][ni] = __builtin_amdgcn_mfma_f32_16x16x32_f16(
                        af[mi], bfr[ni], acc[mi][ni], 0, 0, 0);
            __builtin_amdgcn_s_setprio(0);
        }
        __syncthreads();
    }

    // ---- fused sLSTM epilogue (fully lane-local, incl. C_prev copy) ------
    const size_t BH = (size_t)B_SZ * H_SZ;
    const int j = ((n0 + wn * 64) >> 6) * 16 + fr;    // 0..1023
    const float bvi = bi[j], bvf = bfv[j], bvo = bo[j], bvz = bz[j];

#pragma unroll
    for (int mi = 0; mi < 4; ++mi) {
        const int rbase = m0 + wm * 64 + mi * 16 + kq * 4;
        // batch the 16 loads for this mi-block first (parallel in flight)
        float cp[4], Cp[4], np[4], mp[4];
#pragma unroll
        for (int r2 = 0; r2 < 4; ++r2) {
            const size_t idx = (size_t)(rbase + r2) * H_SZ + j;
            cp[r2] = c_prev[idx];
            Cp[r2] = C_prev[idx];
            np[r2] = n_prev[idx];
            mp[r2] = m_prev[idx];
        }
#pragma unroll
        for (int r2 = 0; r2 < 4; ++r2) {
            const size_t idx = (size_t)(rbase + r2) * H_SZ + j;
            float pi = acc[mi][0][r2] + bvi;
            float pf = acc[mi][1][r2] + bvf;
            float po = acc[mi][2][r2] + bvo;
            float pz = acc[mi][3][r2] + bvz;
            float iv = __expf(pi);
            float fv = 1.0f / (1.0f + __expf(-pf));
            float ov = 1.0f / (1.0f + __expf(-po));
            float e2 = __expf(2.0f * pz);
            float zv = 1.0f - 2.0f / (e2 + 1.0f);     // tanh(pz)
            float cv = fv * cp[r2] + iv * zv;
            float nv = fv * np[r2] + iv;
            float mv = fmaxf(__logf(fv) + mp[r2], pi);
            out[idx]          = ov * (cv / nv);       // h
            out[BH + idx]     = cv;                   // c
            out[2 * BH + idx] = Cp[r2];               // C passthrough
            out[3 * BH + idx] = nv;                   // n
            out[4 * BH + idx] = mv;                   // m
        }
    }
}

// ---------------------------------------------------------------------------
extern "C" void kernel_launch(void* const* d_in, const int* in_sizes, int n_in,
                              void* d_out, int out_size, void* d_ws, size_t ws_size,
                              hipStream_t stream) {
    const float* x      = (const float*)d_in[0];
    const float* h_prev = (const float*)d_in[1];
    const float* c_prev = (const float*)d_in[2];
    const float* C_prev = (const float*)d_in[3];
    const float* n_prev = (const float*)d_in[4];
    const float* m_prev = (const float*)d_in[5];
    const float* Wz = (const float*)d_in[6];
    const float* bz = (const float*)d_in[7];
    const float* Rz = (const float*)d_in[8];
    const float* Wi = (const float*)d_in[9];
    const float* bi = (const float*)d_in[10];
    const float* Ri = (const float*)d_in[11];
    const float* Wf = (const float*)d_in[12];
    const float* bf = (const float*)d_in[13];
    const float* Rf = (const float*)d_in[14];
    const float* Wo = (const float*)d_in[15];
    const float* bo = (const float*)d_in[16];
    const float* Ro = (const float*)d_in[17];
    float* out = (float*)d_out;

    // workspace layout: A_f16 (32MB) | W_f16 (16MB)
    u16* Abuf = (u16*)d_ws;
    u16* Wbuf = (u16*)((char*)d_ws + (size_t)32 * 1024 * 1024);

    convert_AW<<<2048, 256, 0, stream>>>(x, h_prev, Wi, Wf, Wo, Wz,
                                         Ri, Rf, Ro, Rz, Abuf, Wbuf);

    gemm_fused<<<dim3(B_SZ / 128, N4H / 128), 256, 0, stream>>>(
        Abuf, Wbuf, c_prev, C_prev, n_prev, m_prev, bi, bf, bo, bz, out);
}

// Round 7
// 216.152 us; speedup vs baseline: 1.1373x; 1.0118x over previous
//
#include <hip/hip_runtime.h>

// ---------------------------------------------------------------------------
// sLSTM cell, B=8192, D=1024, H=1024.
//   pre[B,4H] = [x,h_prev] @ [Wg|Rg]^T  (K = D+H = 2048)
//   i=exp(pi+bi), f=sig(pf+bf), o=sig(po+bo), z=tanh(pz+bz)
//   c=f*c_prev+i*z ; n=f*n_prev+i ; m=max(log f + m_prev, pi) ; h=o*c/n
//   outputs (flat): h, c, C_prev(copy), n, m  -- each B*H f32
//
// Round 7: deep-pipelined 256x256 GEMM, 4 phases/K-tile, ring-3 A / ring-2 B.
//   8 waves (2M x 4N), per-wave 128x64, acc[8][4], BK=64.
//   LDS: A 3 x 32KB + B 2 x 32KB = 160KB (full CU, 1 block/CU).
//   Per phase q (q=0..3 per tile): {4 ds_read A-quad (+8 ds_read B at q0) ||
//   stage exactly 1 half-tile (2 gload_lds)} -> s_barrier -> setprio(1)
//   16 MFMA setprio(0) -> [vmcnt(8) at q3] -> s_barrier.
//   Stage map for tile T: q0/q1: A(T+2).h0/h1 -> aslot (T+2)%3 (freed: its
//   last reader was tile T-1, ended last tile); q2/q3: B(T+2).h0/h1 -> bslot
//   T&1 (B of tile T read only at q0 -> freed). Lags: A staged 7-8 phases
//   (~1000cy, covers HBM); B 4-6 phases. vmcnt(8) at q3 retires everything
//   except tile T's own 4 half-tile stages => tile T+1 verified landed.
//   vmcnt(0) only at tile 30; tiles 30/31 stage nothing.
// Gate-interleaved W packing -> fused epilogue fully lane-local (incl C_prev).
// ---------------------------------------------------------------------------

#define B_SZ 8192
#define D_SZ 1024
#define H_SZ 1024
#define K_SZ 2048   // D + H
#define N4H  4096   // 4*H

typedef __attribute__((ext_vector_type(4))) float f32x4;
typedef _Float16 f16;
typedef __attribute__((ext_vector_type(8))) f16 f16x8;
typedef unsigned short u16;
typedef __attribute__((ext_vector_type(4))) unsigned short u16x4;

static __device__ __forceinline__ u16 f2h(float f) {
    f16 h = (f16)f;
    return __builtin_bit_cast(unsigned short, h);
}

static __device__ __forceinline__ void load_lds16(const void* g, void* l) {
    __builtin_amdgcn_global_load_lds(
        (const __attribute__((address_space(1))) void*)g,
        (__attribute__((address_space(3))) void*)l, 16, 0, 0);
}

// ---------------------------------------------------------------------------
// Merged pack kernel: A[B][K]=[x|h_prev] fp16; W gate-interleaved fp16
// (packed row r -> gate (r>>4)&3, j=(r>>6)*16+(r&15), content [Wg[j]|Rg[j]]).
// ---------------------------------------------------------------------------
__global__ void convert_AW(const float* __restrict__ x, const float* __restrict__ h,
                           const float* __restrict__ Wi, const float* __restrict__ Wf,
                           const float* __restrict__ Wo, const float* __restrict__ Wz,
                           const float* __restrict__ Ri, const float* __restrict__ Rf,
                           const float* __restrict__ Ro, const float* __restrict__ Rz,
                           u16* __restrict__ A, u16* __restrict__ Wb) {
    const size_t nvecA = (size_t)B_SZ * K_SZ / 4;
    const size_t nvecW = (size_t)N4H * K_SZ / 4;
    const size_t nvec  = nvecA + nvecW;
    const size_t stride = (size_t)gridDim.x * blockDim.x;
    for (size_t v = (size_t)blockIdx.x * blockDim.x + threadIdx.x; v < nvec; v += stride) {
        const float* src;
        u16* dst;
        if (v < nvecA) {
            size_t e = v * 4;
            size_t row = e >> 11;
            int col = (int)(e & 2047);
            src = (col < D_SZ) ? (x + row * D_SZ + col)
                               : (h + row * H_SZ + (col - D_SZ));
            dst = A + e;
        } else {
            size_t e = (v - nvecA) * 4;
            size_t r = e >> 11;
            int col = (int)(e & 2047);
            int g = (int)(r >> 4) & 3;
            int j = (int)((r >> 6) << 4) | (int)(r & 15);
            const float* Wg = (g == 0) ? Wi : (g == 1) ? Wf : (g == 2) ? Wo : Wz;
            const float* Rg = (g == 0) ? Ri : (g == 1) ? Rf : (g == 2) ? Ro : Rz;
            src = (col < D_SZ) ? (Wg + (size_t)j * D_SZ + col)
                               : (Rg + (size_t)j * H_SZ + (col - D_SZ));
            dst = Wb + e;
        }
        f32x4 val = *(const f32x4*)src;
        u16x4 o;
        o[0] = f2h(val[0]); o[1] = f2h(val[1]); o[2] = f2h(val[2]); o[3] = f2h(val[3]);
        *(u16x4*)dst = o;
    }
}

// ---------------------------------------------------------------------------
// Deep-pipelined fused GEMM + sLSTM epilogue. 512 threads, 8 waves.
// ---------------------------------------------------------------------------
__global__ __launch_bounds__(512, 1)
void gemm_fused(const u16* __restrict__ A, const u16* __restrict__ W,
                const float* __restrict__ c_prev, const float* __restrict__ C_prev,
                const float* __restrict__ n_prev, const float* __restrict__ m_prev,
                const float* __restrict__ bi, const float* __restrict__ bfv,
                const float* __restrict__ bo, const float* __restrict__ bz,
                float* __restrict__ out) {
    __shared__ u16 lA[3][256 * 64];   // 96 KB, ring-3
    __shared__ u16 lB[2][256 * 64];   // 64 KB, ring-2   (160 KB total)

    const int tid = threadIdx.x;
    const int w   = tid >> 6;
    const int l   = tid & 63;
    const int wm  = w >> 2;            // 0..1 (128 M-rows)
    const int wn  = w & 3;             // 0..3 (64 packed cols)

    // XCD-aware bijective swizzle: 512 blocks = 32 bm x 16 bn, 64 blocks/XCD.
    // Each XCD owns 2 bn panels (B panel 2x1MB L2-resident), sweeps bm.
    const int xcd = blockIdx.x & 7;
    const int loc = blockIdx.x >> 3;        // 0..63
    const int bm  = loc & 31;
    const int bn  = xcd * 2 + (loc >> 5);   // 0..15
    const int m0  = bm * 256;
    const int n0r = bn * 256;

    const int lrow8 = l >> 3;                            // 0..7
    const int laneOff = lrow8 * K_SZ + ((l & 7) ^ lrow8) * 8;  // pre-swizzled src

    const int fr = l & 15;
    const int kq = l >> 4;

    const u16* Abase = A + (size_t)m0 * K_SZ + laneOff;
    const u16* Bbase = W + (size_t)n0r * K_SZ + laneOff;

    // stage one half-tile (128 rows x 64 K = 2 issues/thread), LDS linear
    auto stA = [&](int h, int kt, int s) {
#pragma unroll
        for (int r = 0; r < 2; ++r)
            load_lds16(Abase + (size_t)(h * 128 + r * 64 + w * 8) * K_SZ + kt * 64,
                       (char*)&lA[s][0] + (h * 128 + r * 64 + w * 8) * 128);
    };
    auto stB = [&](int h, int kt, int s) {
#pragma unroll
        for (int r = 0; r < 2; ++r)
            load_lds16(Bbase + (size_t)(h * 128 + r * 64 + w * 8) * K_SZ + kt * 64,
                       (char*)&lB[s][0] + (h * 128 + r * 64 + w * 8) * 128);
    };

    f32x4 acc[8][4] = {};
    f16x8 bf[4][2];      // B frags, read at q0, live all 4 phases
    f16x8 af[2][2];      // A quad frags, per phase

    auto rdB = [&](int BS) {
#pragma unroll
        for (int ni = 0; ni < 4; ++ni)
#pragma unroll
            for (int ks = 0; ks < 2; ++ks) {
                int row = wn * 64 + ni * 16 + fr;
                int seg = (ks * 4 + kq) ^ (fr & 7);
                bf[ni][ks] = *(const f16x8*)&lB[BS][row * 64 + seg * 8];
            }
    };
    auto rdA = [&](int AS, int q) {
#pragma unroll
        for (int mi2 = 0; mi2 < 2; ++mi2)
#pragma unroll
            for (int ks = 0; ks < 2; ++ks) {
                int row = wm * 128 + (q * 2 + mi2) * 16 + fr;
                int seg = (ks * 4 + kq) ^ (fr & 7);
                af[mi2][ks] = *(const f16x8*)&lA[AS][row * 64 + seg * 8];
            }
    };
    auto mfma_q = [&](int q) {
        __builtin_amdgcn_s_setprio(1);
#pragma unroll
        for (int mi2 = 0; mi2 < 2; ++mi2)
#pragma unroll
            for (int ni = 0; ni < 4; ++ni)
#pragma unroll
                for (int ks = 0; ks < 2; ++ks)
                    acc[q * 2 + mi2][ni] = __builtin_amdgcn_mfma_f32_16x16x32_f16(
                        af[mi2][ks], bf[ni][ks], acc[q * 2 + mi2][ni], 0, 0, 0);
        __builtin_amdgcn_s_setprio(0);
    };

    // one K-tile: AS/BS compile-time slots; KT2<0 => no staging (drain tiles).
    // vmmode: 8 = steady vmcnt(8), 0 = drain vmcnt(0), -1 = none.
    auto tile4 = [&](int AS, int BS, int AST, int KT2, int vmmode) {
        // q0
        rdA(AS, 0); rdB(BS);
        if (KT2 >= 0) stA(0, KT2, AST);
        __builtin_amdgcn_s_barrier();
        mfma_q(0);
        __builtin_amdgcn_s_barrier();
        // q1
        rdA(AS, 1);
        if (KT2 >= 0) stA(1, KT2, AST);
        __builtin_amdgcn_s_barrier();
        mfma_q(1);
        __builtin_amdgcn_s_barrier();
        // q2
        rdA(AS, 2);
        if (KT2 >= 0) stB(0, KT2, BS);
        __builtin_amdgcn_s_barrier();
        mfma_q(2);
        __builtin_amdgcn_s_barrier();
        // q3
        rdA(AS, 3);
        if (KT2 >= 0) stB(1, KT2, BS);
        __builtin_amdgcn_s_barrier();
        mfma_q(3);
        if (vmmode == 8)      asm volatile("s_waitcnt vmcnt(8)" ::: "memory");
        else if (vmmode == 0) asm volatile("s_waitcnt vmcnt(0)" ::: "memory");
        __builtin_amdgcn_s_barrier();
    };

    // prologue: tiles 0,1 fully staged (16 loads); vmcnt(8) -> tile0 landed.
    stA(0, 0, 0); stA(1, 0, 0); stB(0, 0, 0); stB(1, 0, 0);
    stA(0, 1, 1); stA(1, 1, 1); stB(0, 1, 1); stB(1, 1, 1);
    asm volatile("s_waitcnt vmcnt(8)" ::: "memory");
    __builtin_amdgcn_s_barrier();

    // steady: tiles 0..29 (5 groups of 6; A slots period-3, B slots period-2)
#pragma unroll 1
    for (int g = 0; g < 5; ++g) {
        const int T0 = 6 * g;
        tile4(0, 0, 2, T0 + 2, 8);
        tile4(1, 1, 0, T0 + 3, 8);
        tile4(2, 0, 1, T0 + 4, 8);
        tile4(0, 1, 2, T0 + 5, 8);
        tile4(1, 0, 0, T0 + 6, 8);
        tile4(2, 1, 1, T0 + 7, 8);
    }
    // drain: tile 30 (a0,b0) with final vmcnt(0); tile 31 (a1,b1).
    tile4(0, 0, 0, -1, 0);
    tile4(1, 1, 0, -1, -1);

    // ---- fused sLSTM epilogue (fully lane-local, incl. C_prev copy) ------
    const size_t BH = (size_t)B_SZ * H_SZ;
    const int j = ((n0r + wn * 64) >> 6) * 16 + fr;    // 0..1023
    const float bvi = bi[j], bvf = bfv[j], bvo = bo[j], bvz = bz[j];

#pragma unroll
    for (int mi = 0; mi < 8; ++mi) {
        const int rbase = m0 + wm * 128 + mi * 16 + kq * 4;
#pragma unroll
        for (int r2 = 0; r2 < 4; ++r2) {
            const size_t idx = (size_t)(rbase + r2) * H_SZ + j;
            float pi = acc[mi][0][r2] + bvi;
            float pf = acc[mi][1][r2] + bvf;
            float po = acc[mi][2][r2] + bvo;
            float pz = acc[mi][3][r2] + bvz;
            float iv = __expf(pi);
            float fv = 1.0f / (1.0f + __expf(-pf));
            float ov = 1.0f / (1.0f + __expf(-po));
            float e2 = __expf(2.0f * pz);
            float zv = 1.0f - 2.0f / (e2 + 1.0f);     // tanh(pz)
            float cv = fv * c_prev[idx] + iv * zv;
            float nv = fv * n_prev[idx] + iv;
            float mv = fmaxf(__logf(fv) + m_prev[idx], pi);
            out[idx]          = ov * (cv / nv);       // h
            out[BH + idx]     = cv;                   // c
            out[2 * BH + idx] = C_prev[idx];          // C passthrough
            out[3 * BH + idx] = nv;                   // n
            out[4 * BH + idx] = mv;                   // m
        }
    }
}

// ---------------------------------------------------------------------------
extern "C" void kernel_launch(void* const* d_in, const int* in_sizes, int n_in,
                              void* d_out, int out_size, void* d_ws, size_t ws_size,
                              hipStream_t stream) {
    const float* x      = (const float*)d_in[0];
    const float* h_prev = (const float*)d_in[1];
    const float* c_prev = (const float*)d_in[2];
    const float* C_prev = (const float*)d_in[3];
    const float* n_prev = (const float*)d_in[4];
    const float* m_prev = (const float*)d_in[5];
    const float* Wz = (const float*)d_in[6];
    const float* bz = (const float*)d_in[7];
    const float* Rz = (const float*)d_in[8];
    const float* Wi = (const float*)d_in[9];
    const float* bi = (const float*)d_in[10];
    const float* Ri = (const float*)d_in[11];
    const float* Wf = (const float*)d_in[12];
    const float* bf = (const float*)d_in[13];
    const float* Rf = (const float*)d_in[14];
    const float* Wo = (const float*)d_in[15];
    const float* bo = (const float*)d_in[16];
    const float* Ro = (const float*)d_in[17];
    float* out = (float*)d_out;

    // workspace layout: A_f16 (32MB) | W_f16 (16MB)
    u16* Abuf = (u16*)d_ws;
    u16* Wbuf = (u16*)((char*)d_ws + (size_t)32 * 1024 * 1024);

    convert_AW<<<2048, 256, 0, stream>>>(x, h_prev, Wi, Wf, Wo, Wz,
                                         Ri, Rf, Ro, Rz, Abuf, Wbuf);

    gemm_fused<<<dim3(512), 512, 0, stream>>>(
        Abuf, Wbuf, c_prev, C_prev, n_prev, m_prev, bi, bf, bo, bz, out);
}